// Round 1
// baseline (1681.953 us; speedup 1.0000x reference)
//
#include <hip/hip_runtime.h>
#include <cstdint>
#include <cstddef>

#define S_LEN 4096
#define DIM   1024
#define NH    16
#define HD    64
#define QKV_N 3072

// ---------------------------------------------------------------------------
// GEMM: C = A @ B + bias.  A: M×K, B: K×N, row-major, M%128==0, N%128==0, K%16==0
// 128×128 block tile, BK=16, 256 threads, 8×8 micro-tile (4+4 split at +64 so
// LDS float4 reads alias banks at most 2-way, which is free on gfx950).
// ---------------------------------------------------------------------------
__global__ __launch_bounds__(256) void gemm_bias_kernel(
    const float* __restrict__ A, const float* __restrict__ B,
    const float* __restrict__ bias, float* __restrict__ C,
    int M, int N, int K)
{
    __shared__ float As[16][132];   // [k][m] transposed
    __shared__ float Bs[16][132];   // [k][n]
    const int t  = threadIdx.x;
    const int tx = t & 15;
    const int ty = t >> 4;
    const int bm = blockIdx.y * 128;
    const int bn = blockIdx.x * 128;

    float acc[8][8];
#pragma unroll
    for (int i = 0; i < 8; ++i)
#pragma unroll
        for (int j = 0; j < 8; ++j) acc[i][j] = 0.f;

    const int am  = t >> 1;        // 0..127 (A tile row)
    const int ak  = (t & 1) * 8;   // 0 or 8 (A tile k)
    const int bk  = t >> 4;        // 0..15  (B tile k)
    const int bn0 = tx * 8;        // B tile col

    for (int k0 = 0; k0 < K; k0 += 16) {
        const float* ap = A + (size_t)(bm + am) * K + k0 + ak;
        float4 a4a = *(const float4*)ap;
        float4 a4b = *(const float4*)(ap + 4);
        As[ak + 0][am] = a4a.x; As[ak + 1][am] = a4a.y;
        As[ak + 2][am] = a4a.z; As[ak + 3][am] = a4a.w;
        As[ak + 4][am] = a4b.x; As[ak + 5][am] = a4b.y;
        As[ak + 6][am] = a4b.z; As[ak + 7][am] = a4b.w;

        const float* bp = B + (size_t)(k0 + bk) * N + bn + bn0;
        float4 b4a = *(const float4*)bp;
        float4 b4b = *(const float4*)(bp + 4);
        *(float4*)&Bs[bk][bn0]     = b4a;
        *(float4*)&Bs[bk][bn0 + 4] = b4b;

        __syncthreads();
#pragma unroll
        for (int kk = 0; kk < 16; ++kk) {
            float4 a0 = *(const float4*)&As[kk][ty * 4];
            float4 a1 = *(const float4*)&As[kk][64 + ty * 4];
            float4 b0 = *(const float4*)&Bs[kk][tx * 4];
            float4 b1 = *(const float4*)&Bs[kk][64 + tx * 4];
            float av[8] = {a0.x, a0.y, a0.z, a0.w, a1.x, a1.y, a1.z, a1.w};
            float bv[8] = {b0.x, b0.y, b0.z, b0.w, b1.x, b1.y, b1.z, b1.w};
#pragma unroll
            for (int i = 0; i < 8; ++i)
#pragma unroll
                for (int j = 0; j < 8; ++j)
                    acc[i][j] = fmaf(av[i], bv[j], acc[i][j]);
        }
        __syncthreads();
    }

    const float4 bias0 = *(const float4*)&bias[bn + tx * 4];
    const float4 bias1 = *(const float4*)&bias[bn + 64 + tx * 4];
#pragma unroll
    for (int i = 0; i < 8; ++i) {
        const int row = bm + (i < 4 ? ty * 4 + i : 64 + ty * 4 + (i - 4));
        float* cp = C + (size_t)row * N + bn;
        float4 o0 = { acc[i][0] + bias0.x, acc[i][1] + bias0.y,
                      acc[i][2] + bias0.z, acc[i][3] + bias0.w };
        float4 o1 = { acc[i][4] + bias1.x, acc[i][5] + bias1.y,
                      acc[i][6] + bias1.z, acc[i][7] + bias1.w };
        *(float4*)(cp + tx * 4)      = o0;
        *(float4*)(cp + 64 + tx * 4) = o1;
    }
}

// ---------------------------------------------------------------------------
// RoPE in-place on q and k halves of qkv (rows S×3072; q at col 0, k at 1024).
// rotate_half over the FULL model dim (1024): pair (j, j+512), j<512.
// One thread per (s, which∈{q,k}, j) — pairs are disjoint, in-place is safe.
// ---------------------------------------------------------------------------
__global__ void rope_kernel(float* __restrict__ qkv)
{
    const int idx   = blockIdx.x * blockDim.x + threadIdx.x; // S*2*512 total
    const int j     = idx & 511;
    const int rest  = idx >> 9;
    const int which = rest & 1;   // 0 = q, 1 = k
    const int s     = rest >> 1;
    float* p = qkv + (size_t)s * QKV_N + which * DIM;
    // inv_freq = 10000^(-j/512) = exp(-j*ln(10000)/512)
    const float inv_freq = __expf((float)j * (-9.210340371976184f / 512.0f));
    const float ang = (float)s * inv_freq;
    float sn, cs;
    sincosf(ang, &sn, &cs);
    const float x1 = p[j];
    const float x2 = p[j + 512];
    p[j]       = x1 * cs - x2 * sn;   // x*cos + (-x[j+512])*sin
    p[j + 512] = x2 * cs + x1 * sn;   // x*cos + ( x[j-512])*sin
}

// ---------------------------------------------------------------------------
// Flash attention, causal, fp32. One block = (head, 64 q-rows), 256 threads.
// 64-key tiles; thread owns a 4×4 micro-tile (rows ty*4+i, cols tx*4+j).
// Online softmax per row via 16-lane shuffle reduction (row is owned by 16
// consecutive lanes of one wave). Q pre-scaled by 1/sqrt(64)=0.125.
// ---------------------------------------------------------------------------
__global__ __launch_bounds__(256) void attn_kernel(
    const float* __restrict__ qkv, float* __restrict__ out)
{
    __shared__ float Qs[HD][68];   // [d][m], pre-scaled
    __shared__ float Ks[HD][68];   // [d][c]
    __shared__ float Vs[64][68];   // [c][d]
    __shared__ float Ps[64][68];   // [c][m]

    const int t  = threadIdx.x;
    const int tx = t & 15;
    const int ty = t >> 4;
    const int h  = blockIdx.y;
    const int q0 = blockIdx.x * 64;

    // Load Q tile (64 rows × 64 dims), scale, store transposed [d][m]
    {
        const int m = t >> 2, d0 = (t & 3) * 16;
        const float* qp = qkv + (size_t)(q0 + m) * QKV_N + h * HD + d0;
#pragma unroll
        for (int u = 0; u < 4; ++u) {
            float4 v = *(const float4*)(qp + u * 4);
            Qs[d0 + u * 4 + 0][m] = v.x * 0.125f;
            Qs[d0 + u * 4 + 1][m] = v.y * 0.125f;
            Qs[d0 + u * 4 + 2][m] = v.z * 0.125f;
            Qs[d0 + u * 4 + 3][m] = v.w * 0.125f;
        }
    }

    float o[4][4];
#pragma unroll
    for (int i = 0; i < 4; ++i)
#pragma unroll
        for (int j = 0; j < 4; ++j) o[i][j] = 0.f;
    float mrow[4] = {-1e30f, -1e30f, -1e30f, -1e30f};
    float lrow[4] = {0.f, 0.f, 0.f, 0.f};

    const int ntiles = (q0 >> 6) + 1;   // causal: k-tiles 0..q0/64
    for (int kt = 0; kt < ntiles; ++kt) {
        const int k0 = kt << 6;
        __syncthreads();   // prev PV done (and Q stores visible on iter 0)
        {
            const int c = t >> 2, d0 = (t & 3) * 16;
            const float* kp = qkv + (size_t)(k0 + c) * QKV_N + DIM     + h * HD + d0;
            const float* vp = qkv + (size_t)(k0 + c) * QKV_N + 2 * DIM + h * HD + d0;
#pragma unroll
            for (int u = 0; u < 4; ++u) {
                float4 kv = *(const float4*)(kp + u * 4);
                Ks[d0 + u * 4 + 0][c] = kv.x;
                Ks[d0 + u * 4 + 1][c] = kv.y;
                Ks[d0 + u * 4 + 2][c] = kv.z;
                Ks[d0 + u * 4 + 3][c] = kv.w;
                *(float4*)&Vs[c][d0 + u * 4] = *(const float4*)(vp + u * 4);
            }
        }
        __syncthreads();

        // S = (Q/8) · Kᵀ  (4×4 per thread)
        float sc[4][4];
#pragma unroll
        for (int i = 0; i < 4; ++i)
#pragma unroll
            for (int j = 0; j < 4; ++j) sc[i][j] = 0.f;
#pragma unroll 8
        for (int d = 0; d < 64; ++d) {
            float4 a = *(const float4*)&Qs[d][ty * 4];
            float4 b = *(const float4*)&Ks[d][tx * 4];
            float av[4] = {a.x, a.y, a.z, a.w};
            float bv[4] = {b.x, b.y, b.z, b.w};
#pragma unroll
            for (int i = 0; i < 4; ++i)
#pragma unroll
                for (int j = 0; j < 4; ++j)
                    sc[i][j] = fmaf(av[i], bv[j], sc[i][j]);
        }

        if (k0 == q0) {   // diagonal tile: mask k_global > q_global
#pragma unroll
            for (int i = 0; i < 4; ++i)
#pragma unroll
                for (int j = 0; j < 4; ++j)
                    if (tx * 4 + j > ty * 4 + i) sc[i][j] = -1e30f;
        }

        // online softmax (rows owned by 16 consecutive lanes: shfl_xor 1,2,4,8)
#pragma unroll
        for (int i = 0; i < 4; ++i) {
            float tm = fmaxf(fmaxf(sc[i][0], sc[i][1]), fmaxf(sc[i][2], sc[i][3]));
            tm = fmaxf(tm, __shfl_xor(tm, 1));
            tm = fmaxf(tm, __shfl_xor(tm, 2));
            tm = fmaxf(tm, __shfl_xor(tm, 4));
            tm = fmaxf(tm, __shfl_xor(tm, 8));
            const float mnew  = fmaxf(mrow[i], tm);
            const float alpha = __expf(mrow[i] - mnew);
            mrow[i] = mnew;
            float ps = 0.f;
#pragma unroll
            for (int j = 0; j < 4; ++j) {
                const float p = __expf(sc[i][j] - mnew);
                sc[i][j] = p;
                ps += p;
            }
            ps += __shfl_xor(ps, 1);
            ps += __shfl_xor(ps, 2);
            ps += __shfl_xor(ps, 4);
            ps += __shfl_xor(ps, 8);
            lrow[i] = lrow[i] * alpha + ps;
#pragma unroll
            for (int j = 0; j < 4; ++j) {
                o[i][j] *= alpha;
                Ps[tx * 4 + j][ty * 4 + i] = sc[i][j];   // store P transposed [c][m]
            }
        }
        __syncthreads();

        // O += P · V  (4×4 per thread: rows m=ty*4+i, dims d=tx*4+j)
#pragma unroll 8
        for (int c = 0; c < 64; ++c) {
            float4 a = *(const float4*)&Ps[c][ty * 4];
            float4 b = *(const float4*)&Vs[c][tx * 4];
            float av[4] = {a.x, a.y, a.z, a.w};
            float bv[4] = {b.x, b.y, b.z, b.w};
#pragma unroll
            for (int i = 0; i < 4; ++i)
#pragma unroll
                for (int j = 0; j < 4; ++j)
                    o[i][j] = fmaf(av[i], bv[j], o[i][j]);
        }
    }

    // epilogue: normalize and store (out is S×DIM, head-major layout)
#pragma unroll
    for (int i = 0; i < 4; ++i) {
        const float inv = 1.0f / lrow[i];
        const int row = q0 + ty * 4 + i;
        float4 ov = { o[i][0] * inv, o[i][1] * inv, o[i][2] * inv, o[i][3] * inv };
        *(float4*)&out[(size_t)row * DIM + h * HD + tx * 4] = ov;
    }
}

// ---------------------------------------------------------------------------
// LayerNorm per row (1024 elems), gamma/beta affine. 256 threads/row.
// ---------------------------------------------------------------------------
__global__ __launch_bounds__(256) void ln_kernel(
    const float* __restrict__ in, const float* __restrict__ gamma,
    const float* __restrict__ beta, float* __restrict__ out)
{
    const int row = blockIdx.x;
    const int t = threadIdx.x;
    const float4 v = *(const float4*)&in[(size_t)row * DIM + t * 4];
    float s  = v.x + v.y + v.z + v.w;
    float sq = v.x * v.x + v.y * v.y + v.z * v.z + v.w * v.w;
#pragma unroll
    for (int off = 1; off < 64; off <<= 1) {
        s  += __shfl_xor(s, off);
        sq += __shfl_xor(sq, off);
    }
    __shared__ float red[8];
    const int wv = t >> 6, ln = t & 63;
    if (ln == 0) { red[wv] = s; red[4 + wv] = sq; }
    __syncthreads();
    s  = red[0] + red[1] + red[2] + red[3];
    sq = red[4] + red[5] + red[6] + red[7];
    const float mu  = s * (1.0f / DIM);
    const float var = sq * (1.0f / DIM) - mu * mu;
    const float rs  = rsqrtf(var + 1e-5f);
    const float4 g = *(const float4*)&gamma[t * 4];
    const float4 b = *(const float4*)&beta[t * 4];
    float4 o = { (v.x - mu) * rs * g.x + b.x,
                 (v.y - mu) * rs * g.y + b.y,
                 (v.z - mu) * rs * g.z + b.z,
                 (v.w - mu) * rs * g.w + b.w };
    *(float4*)&out[(size_t)row * DIM + t * 4] = o;
}

// ---------------------------------------------------------------------------
extern "C" void kernel_launch(void* const* d_in, const int* in_sizes, int n_in,
                              void* d_out, int out_size, void* d_ws, size_t ws_size,
                              hipStream_t stream)
{
    const float* x     = (const float*)d_in[0];
    const float* Wqkv  = (const float*)d_in[1];
    const float* bqkv  = (const float*)d_in[2];
    const float* Wo    = (const float*)d_in[3];
    const float* bo    = (const float*)d_in[4];
    const float* gamma = (const float*)d_in[5];
    const float* beta  = (const float*)d_in[6];
    float* out = (float*)d_out;

    // workspace: qkv (4096×3072 f32 = 48 MB) | attn (4096×1024 f32 = 16 MB)
    float* qkv  = (float*)d_ws;
    float* attn = qkv + (size_t)S_LEN * QKV_N;
    float* proj = qkv;   // reuse qkv region after attention is done

    gemm_bias_kernel<<<dim3(QKV_N / 128, S_LEN / 128), 256, 0, stream>>>(
        x, Wqkv, bqkv, qkv, S_LEN, QKV_N, DIM);
    rope_kernel<<<(S_LEN * 2 * 512) / 256, 256, 0, stream>>>(qkv);
    attn_kernel<<<dim3(S_LEN / 64, NH), 256, 0, stream>>>(qkv, attn);
    gemm_bias_kernel<<<dim3(DIM / 128, S_LEN / 128), 256, 0, stream>>>(
        attn, Wo, bo, proj, S_LEN, DIM, DIM);
    ln_kernel<<<S_LEN, 256, 0, stream>>>(proj, gamma, beta, out);
}

// Round 2
// 833.600 us; speedup vs baseline: 2.0177x; 2.0177x over previous
//
#include <hip/hip_runtime.h>
#include <cstdint>
#include <cstddef>

#define S_LEN 4096
#define DIM   1024
#define NH    16
#define HD    64
#define QKV_N 3072

typedef __attribute__((ext_vector_type(8))) short short8;     // 8 bf16 (A/B frag)
typedef __attribute__((ext_vector_type(4))) float f32x4;      // C/D frag
typedef __attribute__((ext_vector_type(4))) unsigned short ushort4v;

__device__ inline unsigned short f2bf(float x) {   // RNE float->bf16
    unsigned int u = __builtin_bit_cast(unsigned int, x);
    u += 0x7fffu + ((u >> 16) & 1u);
    return (unsigned short)(u >> 16);
}

// ---------------------------------------------------------------------------
// fp32 GEMM: C = A @ B + bias (unchanged from round 1)
// ---------------------------------------------------------------------------
__global__ __launch_bounds__(256) void gemm_bias_kernel(
    const float* __restrict__ A, const float* __restrict__ B,
    const float* __restrict__ bias, float* __restrict__ C,
    int M, int N, int K)
{
    __shared__ float As[16][132];
    __shared__ float Bs[16][132];
    const int t  = threadIdx.x;
    const int tx = t & 15;
    const int ty = t >> 4;
    const int bm = blockIdx.y * 128;
    const int bn = blockIdx.x * 128;

    float acc[8][8];
#pragma unroll
    for (int i = 0; i < 8; ++i)
#pragma unroll
        for (int j = 0; j < 8; ++j) acc[i][j] = 0.f;

    const int am  = t >> 1;
    const int ak  = (t & 1) * 8;
    const int bk  = t >> 4;
    const int bn0 = tx * 8;

    for (int k0 = 0; k0 < K; k0 += 16) {
        const float* ap = A + (size_t)(bm + am) * K + k0 + ak;
        float4 a4a = *(const float4*)ap;
        float4 a4b = *(const float4*)(ap + 4);
        As[ak + 0][am] = a4a.x; As[ak + 1][am] = a4a.y;
        As[ak + 2][am] = a4a.z; As[ak + 3][am] = a4a.w;
        As[ak + 4][am] = a4b.x; As[ak + 5][am] = a4b.y;
        As[ak + 6][am] = a4b.z; As[ak + 7][am] = a4b.w;

        const float* bp = B + (size_t)(k0 + bk) * N + bn + bn0;
        float4 b4a = *(const float4*)bp;
        float4 b4b = *(const float4*)(bp + 4);
        *(float4*)&Bs[bk][bn0]     = b4a;
        *(float4*)&Bs[bk][bn0 + 4] = b4b;

        __syncthreads();
#pragma unroll
        for (int kk = 0; kk < 16; ++kk) {
            float4 a0 = *(const float4*)&As[kk][ty * 4];
            float4 a1 = *(const float4*)&As[kk][64 + ty * 4];
            float4 b0 = *(const float4*)&Bs[kk][tx * 4];
            float4 b1 = *(const float4*)&Bs[kk][64 + tx * 4];
            float av[8] = {a0.x, a0.y, a0.z, a0.w, a1.x, a1.y, a1.z, a1.w};
            float bv[8] = {b0.x, b0.y, b0.z, b0.w, b1.x, b1.y, b1.z, b1.w};
#pragma unroll
            for (int i = 0; i < 8; ++i)
#pragma unroll
                for (int j = 0; j < 8; ++j)
                    acc[i][j] = fmaf(av[i], bv[j], acc[i][j]);
        }
        __syncthreads();
    }

    const float4 bias0 = *(const float4*)&bias[bn + tx * 4];
    const float4 bias1 = *(const float4*)&bias[bn + 64 + tx * 4];
#pragma unroll
    for (int i = 0; i < 8; ++i) {
        const int row = bm + (i < 4 ? ty * 4 + i : 64 + ty * 4 + (i - 4));
        float* cp = C + (size_t)row * N + bn;
        float4 o0 = { acc[i][0] + bias0.x, acc[i][1] + bias0.y,
                      acc[i][2] + bias0.z, acc[i][3] + bias0.w };
        float4 o1 = { acc[i][4] + bias1.x, acc[i][5] + bias1.y,
                      acc[i][6] + bias1.z, acc[i][7] + bias1.w };
        *(float4*)(cp + tx * 4)      = o0;
        *(float4*)(cp + 64 + tx * 4) = o1;
    }
}

// ---------------------------------------------------------------------------
// Prepass: RoPE(q,k) + bf16 convert; Q pre-scaled by 0.125*log2(e) (softmax
// then uses exp2). V transposed to Vt[dim][s] bf16 via LDS tile transpose.
// One block per 64 rows.
// ---------------------------------------------------------------------------
__global__ __launch_bounds__(256) void prepass_kernel(
    const float* __restrict__ qkv,
    unsigned short* __restrict__ Qb,
    unsigned short* __restrict__ Kb,
    unsigned short* __restrict__ Vt)
{
    __shared__ unsigned short Ls[64][72];
    const int t = threadIdx.x;
    const int b = blockIdx.x;
    const float QSCALE = 0.18033688011112042f;   // 0.125 * log2(e)

    // --- RoPE + convert Q, K ---
    {
        const int rl = t >> 2;
        const int j0 = (t & 3) * 128;
        const int s  = b * 64 + rl;
        const float* row = qkv + (size_t)s * QKV_N;
        unsigned short* qo = Qb + (size_t)s * DIM;
        unsigned short* ko = Kb + (size_t)s * DIM;
        const float sf = (float)s;
        for (int jj = 0; jj < 128; jj += 4) {
            const int j = j0 + jj;
            float cs[4], sn[4];
#pragma unroll
            for (int e = 0; e < 4; ++e) {
                const float invf = __expf((float)(j + e) * (-9.210340371976184f / 512.0f));
                sincosf(sf * invf, &sn[e], &cs[e]);
            }
            float4 q1 = *(const float4*)(row + j);
            float4 q2 = *(const float4*)(row + 512 + j);
            float4 k1 = *(const float4*)(row + DIM + j);
            float4 k2 = *(const float4*)(row + DIM + 512 + j);
            float x1[4] = {q1.x, q1.y, q1.z, q1.w};
            float x2[4] = {q2.x, q2.y, q2.z, q2.w};
            float y1[4] = {k1.x, k1.y, k1.z, k1.w};
            float y2[4] = {k2.x, k2.y, k2.z, k2.w};
            ushort4v qa, qb4, ka, kb4;
#pragma unroll
            for (int e = 0; e < 4; ++e) {
                qa[e]  = f2bf((x1[e] * cs[e] - x2[e] * sn[e]) * QSCALE);
                qb4[e] = f2bf((x2[e] * cs[e] + x1[e] * sn[e]) * QSCALE);
                ka[e]  = f2bf(y1[e] * cs[e] - y2[e] * sn[e]);
                kb4[e] = f2bf(y2[e] * cs[e] + y1[e] * sn[e]);
            }
            *(ushort4v*)(qo + j)       = qa;
            *(ushort4v*)(qo + 512 + j) = qb4;
            *(ushort4v*)(ko + j)       = ka;
            *(ushort4v*)(ko + 512 + j) = kb4;
        }
    }

    // --- V: convert + transpose, 16 column tiles of 64 ---
    const int sl = t >> 2;
    const int cb = (t & 3) * 16;
    const int cl = t >> 2;
    const int sb = (t & 3) * 16;
    for (int ct = 0; ct < 16; ++ct) {
        __syncthreads();
        const float* vp = qkv + (size_t)(b * 64 + sl) * QKV_N + 2 * DIM + ct * 64 + cb;
#pragma unroll
        for (int u = 0; u < 16; u += 4) {
            float4 v4 = *(const float4*)(vp + u);
            ushort4v pk = { f2bf(v4.x), f2bf(v4.y), f2bf(v4.z), f2bf(v4.w) };
            *(ushort4v*)&Ls[sl][cb + u] = pk;
        }
        __syncthreads();
        short8 lo, hi;
#pragma unroll
        for (int u = 0; u < 8; ++u) lo[u] = (short)Ls[sb + u][cl];
#pragma unroll
        for (int u = 0; u < 8; ++u) hi[u] = (short)Ls[sb + 8 + u][cl];
        unsigned short* op = Vt + (size_t)(ct * 64 + cl) * S_LEN + b * 64 + sb;
        *(short8*)op       = lo;
        *(short8*)(op + 8) = hi;
    }
}

// ---------------------------------------------------------------------------
// MFMA flash attention (bf16, causal). Block = (head, 64 q-rows), 4 waves.
// Wave w owns q-row strip [w*16, w*16+16). 16x16x32 MFMA.
// A-frag: X[m=lane&15][k=quad*8+j]; B-frag: X[k=quad*8+j][n=lane&15];
// C/D: col=lane&15, row=quad*4+reg (verified m89/m120).
// ---------------------------------------------------------------------------
__global__ __launch_bounds__(256) void attn_mfma_kernel(
    const unsigned short* __restrict__ Qb,
    const unsigned short* __restrict__ Kb,
    const unsigned short* __restrict__ Vt,
    float* __restrict__ out)
{
    __shared__ unsigned short Ks[64][72];   // [c][d]
    __shared__ unsigned short Vs[64][72];   // [d][c]  (from Vt)
    __shared__ unsigned short Ps[64][72];   // [m][c]  (wave-local strips)

    const int t    = threadIdx.x;
    const int w    = t >> 6;
    const int lane = t & 63;
    const int ln   = lane & 15;
    const int quad = lane >> 4;
    const int h    = blockIdx.y;
    const int qt   = (int)(gridDim.x - 1) - (int)blockIdx.x;  // heavy tiles first
    const int q0   = qt * 64;

    short8 qf[2];
    {
        const unsigned short* qp = Qb + (size_t)(q0 + w * 16 + ln) * DIM + h * HD + quad * 8;
        qf[0] = *(const short8*)qp;
        qf[1] = *(const short8*)(qp + 32);
    }

    f32x4 o[4];
#pragma unroll
    for (int db = 0; db < 4; ++db) o[db] = (f32x4){0.f, 0.f, 0.f, 0.f};
    float mrow[4] = {-1e30f, -1e30f, -1e30f, -1e30f};
    float lrow[4] = {0.f, 0.f, 0.f, 0.f};

    for (int kt = 0; kt <= qt; ++kt) {
        const int k0 = kt * 64;
        __syncthreads();   // prior iter's Ks/Vs reads complete
        {
            const int c   = t >> 2;
            const int off = (t & 3) * 16;
            const unsigned short* kp = Kb + (size_t)(k0 + c) * DIM + h * HD + off;
            *(short8*)&Ks[c][off]     = *(const short8*)kp;
            *(short8*)&Ks[c][off + 8] = *(const short8*)(kp + 8);
            const unsigned short* vp = Vt + (size_t)(h * HD + c) * S_LEN + k0 + off;
            *(short8*)&Vs[c][off]     = *(const short8*)vp;
            *(short8*)&Vs[c][off + 8] = *(const short8*)(vp + 8);
        }
        __syncthreads();

        // S = Q·K^T  (wave strip: 16 rows × 64 cols)
        f32x4 sc[4];
#pragma unroll
        for (int nb = 0; nb < 4; ++nb) sc[nb] = (f32x4){0.f, 0.f, 0.f, 0.f};
#pragma unroll
        for (int kk = 0; kk < 2; ++kk) {
#pragma unroll
            for (int nb = 0; nb < 4; ++nb) {
                short8 bfr = *(const short8*)&Ks[nb * 16 + ln][kk * 32 + quad * 8];
                sc[nb] = __builtin_amdgcn_mfma_f32_16x16x32_bf16(qf[kk], bfr, sc[nb], 0, 0, 0);
            }
        }

        if (kt == qt) {   // diagonal tile: mask col > row
#pragma unroll
            for (int nb = 0; nb < 4; ++nb) {
                const int col = nb * 16 + ln;
#pragma unroll
                for (int r = 0; r < 4; ++r)
                    if (col > w * 16 + quad * 4 + r) sc[nb][r] = -1e30f;
            }
        }

        // online softmax (scores are pre-scaled by log2e; use exp2)
#pragma unroll
        for (int r = 0; r < 4; ++r) {
            float tm = fmaxf(fmaxf(sc[0][r], sc[1][r]), fmaxf(sc[2][r], sc[3][r]));
            tm = fmaxf(tm, __shfl_xor(tm, 1));
            tm = fmaxf(tm, __shfl_xor(tm, 2));
            tm = fmaxf(tm, __shfl_xor(tm, 4));
            tm = fmaxf(tm, __shfl_xor(tm, 8));
            const float mnew = fmaxf(mrow[r], tm);
            const float al   = exp2f(mrow[r] - mnew);
            mrow[r] = mnew;
            float ps = 0.f;
#pragma unroll
            for (int nb = 0; nb < 4; ++nb) {
                const float p = exp2f(sc[nb][r] - mnew);
                ps += p;
                Ps[w * 16 + quad * 4 + r][nb * 16 + ln] = f2bf(p);
            }
            ps += __shfl_xor(ps, 1);
            ps += __shfl_xor(ps, 2);
            ps += __shfl_xor(ps, 4);
            ps += __shfl_xor(ps, 8);
            lrow[r] = lrow[r] * al + ps;
#pragma unroll
            for (int db = 0; db < 4; ++db) o[db][r] *= al;
        }

        // O += P·V   (Ps strip is wave-local; in-wave LDS ordering suffices)
#pragma unroll
        for (int kk = 0; kk < 2; ++kk) {
            short8 pa = *(const short8*)&Ps[w * 16 + ln][kk * 32 + quad * 8];
#pragma unroll
            for (int db = 0; db < 4; ++db) {
                short8 vb = *(const short8*)&Vs[db * 16 + ln][kk * 32 + quad * 8];
                o[db] = __builtin_amdgcn_mfma_f32_16x16x32_bf16(pa, vb, o[db], 0, 0, 0);
            }
        }
    }

    // epilogue: normalize, store fp32
#pragma unroll
    for (int r = 0; r < 4; ++r) {
        const float inv = 1.0f / lrow[r];
        float* op = out + (size_t)(q0 + w * 16 + quad * 4 + r) * DIM + h * HD;
#pragma unroll
        for (int db = 0; db < 4; ++db)
            op[db * 16 + ln] = o[db][r] * inv;
    }
}

// ---------------------------------------------------------------------------
// LayerNorm per row (unchanged)
// ---------------------------------------------------------------------------
__global__ __launch_bounds__(256) void ln_kernel(
    const float* __restrict__ in, const float* __restrict__ gamma,
    const float* __restrict__ beta, float* __restrict__ out)
{
    const int row = blockIdx.x;
    const int t = threadIdx.x;
    const float4 v = *(const float4*)&in[(size_t)row * DIM + t * 4];
    float s  = v.x + v.y + v.z + v.w;
    float sq = v.x * v.x + v.y * v.y + v.z * v.z + v.w * v.w;
#pragma unroll
    for (int off = 1; off < 64; off <<= 1) {
        s  += __shfl_xor(s, off);
        sq += __shfl_xor(sq, off);
    }
    __shared__ float red[8];
    const int wv = t >> 6, ln = t & 63;
    if (ln == 0) { red[wv] = s; red[4 + wv] = sq; }
    __syncthreads();
    s  = red[0] + red[1] + red[2] + red[3];
    sq = red[4] + red[5] + red[6] + red[7];
    const float mu  = s * (1.0f / DIM);
    const float var = sq * (1.0f / DIM) - mu * mu;
    const float rs  = rsqrtf(var + 1e-5f);
    const float4 g = *(const float4*)&gamma[t * 4];
    const float4 b = *(const float4*)&beta[t * 4];
    float4 o = { (v.x - mu) * rs * g.x + b.x,
                 (v.y - mu) * rs * g.y + b.y,
                 (v.z - mu) * rs * g.z + b.z,
                 (v.w - mu) * rs * g.w + b.w };
    *(float4*)&out[(size_t)row * DIM + t * 4] = o;
}

// ---------------------------------------------------------------------------
extern "C" void kernel_launch(void* const* d_in, const int* in_sizes, int n_in,
                              void* d_out, int out_size, void* d_ws, size_t ws_size,
                              hipStream_t stream)
{
    const float* x     = (const float*)d_in[0];
    const float* Wqkv  = (const float*)d_in[1];
    const float* bqkv  = (const float*)d_in[2];
    const float* Wo    = (const float*)d_in[3];
    const float* bo    = (const float*)d_in[4];
    const float* gamma = (const float*)d_in[5];
    const float* beta  = (const float*)d_in[6];
    float* out = (float*)d_out;

    // ws layout: qkv fp32 48MB | Qb bf16 8MB | Kb bf16 8MB | Vt bf16 8MB = 72MB
    // attn out (fp32 16MB) and proj out (fp32 16MB) reuse the dead qkv region.
    float* qkv = (float*)d_ws;
    unsigned short* Qb = (unsigned short*)(qkv + (size_t)S_LEN * QKV_N);
    unsigned short* Kb = Qb + (size_t)S_LEN * DIM;
    unsigned short* Vt = Kb + (size_t)S_LEN * DIM;
    float* attn = qkv;
    float* proj = qkv + (size_t)S_LEN * DIM;

    gemm_bias_kernel<<<dim3(QKV_N / 128, S_LEN / 128), 256, 0, stream>>>(
        x, Wqkv, bqkv, qkv, S_LEN, QKV_N, DIM);
    prepass_kernel<<<S_LEN / 64, 256, 0, stream>>>(qkv, Qb, Kb, Vt);
    attn_mfma_kernel<<<dim3(S_LEN / 64, NH), 256, 0, stream>>>(Qb, Kb, Vt, attn);
    gemm_bias_kernel<<<dim3(DIM / 128, S_LEN / 128), 256, 0, stream>>>(
        attn, Wo, bo, proj, S_LEN, DIM, DIM);
    ln_kernel<<<S_LEN, 256, 0, stream>>>(proj, gamma, beta, out);
}

// Round 3
// 412.897 us; speedup vs baseline: 4.0735x; 2.0189x over previous
//
#include <hip/hip_runtime.h>
#include <cstdint>
#include <cstddef>

#define S_LEN 4096
#define DIM   1024
#define NH    16
#define HD    64
#define QKV_N 3072

typedef __attribute__((ext_vector_type(8))) short short8;     // 8 bf16
typedef __attribute__((ext_vector_type(4))) float f32x4;      // MFMA C/D frag
typedef __attribute__((ext_vector_type(4))) unsigned short ushort4v;

__device__ inline unsigned short f2bf(float x) {   // RNE float->bf16
    unsigned int u = __builtin_bit_cast(unsigned int, x);
    u += 0x7fffu + ((u >> 16) & 1u);
    return (unsigned short)(u >> 16);
}

// async global->LDS, 16B per lane; LDS dest = wave-uniform base + lane*16
__device__ inline void gl_lds16(const void* g, void* l) {
    __builtin_amdgcn_global_load_lds(
        (const __attribute__((address_space(1))) void*)g,
        (__attribute__((address_space(3))) void*)l, 16, 0, 0);
}

// ---------------------------------------------------------------------------
// bf16 MFMA GEMM (m97 structure): C = A @ Bt^T + bias.
// A: M×K bf16 row-major. Bt: N×K bf16 row-major (i.e. B transposed).
// C: M×N fp32. 128×128 tile, BK=32, 256 threads (4 waves, 2×2 wave grid).
// ---------------------------------------------------------------------------
__global__ __launch_bounds__(256) void gemm_mfma_kernel(
    const unsigned short* __restrict__ A,
    const unsigned short* __restrict__ Bt,
    const float* __restrict__ bias,
    float* __restrict__ C,
    int M, int N, int K)
{
    __shared__ unsigned short As[128 * 32];   // [m][k], k contiguous (no pad: glds)
    __shared__ unsigned short Bs[128 * 32];   // [n][k]

    const int t    = threadIdx.x;
    const int w    = t >> 6;
    const int lane = t & 63;
    const int ln   = lane & 15;
    const int quad = lane >> 4;
    const int bm   = blockIdx.y * 128;
    const int bn   = blockIdx.x * 128;
    const int wm   = (w & 1) * 64;
    const int wn   = (w >> 1) * 64;

    f32x4 acc[4][4];
#pragma unroll
    for (int i = 0; i < 4; ++i)
#pragma unroll
        for (int j = 0; j < 4; ++j) acc[i][j] = (f32x4){0.f, 0.f, 0.f, 0.f};

    // staging addresses: wave w covers rows [w*32, w*32+32) of each tile,
    // 2 glds instrs of 16 rows; lane covers row lane/4, 8 elems at (lane%4)*8.
    const int lr = lane >> 2;
    const int lc = (lane & 3) * 8;
    const unsigned short* ga = A  + (size_t)(bm + w * 32 + lr) * K + lc;
    const unsigned short* gb = Bt + (size_t)(bn + w * 32 + lr) * K + lc;
    unsigned short* la = &As[(w * 32) * 32];
    unsigned short* lb = &Bs[(w * 32) * 32];

    for (int k0 = 0; k0 < K; k0 += 32) {
        gl_lds16(ga,            la);
        gl_lds16(ga + 16 * K,   la + 16 * 32);
        gl_lds16(gb,            lb);
        gl_lds16(gb + 16 * K,   lb + 16 * 32);
        ga += 32; gb += 32;
        __syncthreads();   // drains vmcnt (glds) for all waves

        short8 af[4], bf[4];
#pragma unroll
        for (int i = 0; i < 4; ++i)
            af[i] = *(const short8*)&As[(wm + i * 16 + ln) * 32 + quad * 8];
#pragma unroll
        for (int j = 0; j < 4; ++j)
            bf[j] = *(const short8*)&Bs[(wn + j * 16 + ln) * 32 + quad * 8];
#pragma unroll
        for (int i = 0; i < 4; ++i)
#pragma unroll
            for (int j = 0; j < 4; ++j)
                acc[i][j] = __builtin_amdgcn_mfma_f32_16x16x32_bf16(af[i], bf[j], acc[i][j], 0, 0, 0);
        __syncthreads();   // reads done before next stage overwrites
    }

    // epilogue: bias + fp32 store. C/D layout: col=ln, row=quad*4+r.
#pragma unroll
    for (int j = 0; j < 4; ++j) {
        const int col = bn + wn + j * 16 + ln;
        const float bv = bias[col];
#pragma unroll
        for (int i = 0; i < 4; ++i) {
            const int row0 = bm + wm + i * 16 + quad * 4;
#pragma unroll
            for (int r = 0; r < 4; ++r)
                C[(size_t)(row0 + r) * N + col] = acc[i][j][r] + bv;
        }
    }
}

// ---------------------------------------------------------------------------
// fp32 -> bf16 elementwise convert (8 elems/thread)
// ---------------------------------------------------------------------------
__global__ __launch_bounds__(256) void cvt_bf16_kernel(
    const float* __restrict__ in, unsigned short* __restrict__ out)
{
    const size_t i = ((size_t)blockIdx.x * 256 + threadIdx.x) * 8;
    float4 a = *(const float4*)(in + i);
    float4 b = *(const float4*)(in + i + 4);
    short8 p = { (short)f2bf(a.x), (short)f2bf(a.y), (short)f2bf(a.z), (short)f2bf(a.w),
                 (short)f2bf(b.x), (short)f2bf(b.y), (short)f2bf(b.z), (short)f2bf(b.w) };
    *(short8*)(out + i) = p;
}

// ---------------------------------------------------------------------------
// Weight transpose + convert: W (K×N fp32, row-major) -> Wt (N×K bf16).
// 64×64 tiles via LDS. grid = (N/64, K/64).
// ---------------------------------------------------------------------------
__global__ __launch_bounds__(256) void wtrans_kernel(
    const float* __restrict__ W, unsigned short* __restrict__ Wt, int K, int N)
{
    __shared__ unsigned short L[64][72];
    const int t  = threadIdx.x;
    const int k0 = blockIdx.y * 64;
    const int n0 = blockIdx.x * 64;

    const int kr = t >> 2, cb = (t & 3) * 16;
    const float* wp = W + (size_t)(k0 + kr) * N + n0 + cb;
#pragma unroll
    for (int u = 0; u < 16; u += 4) {
        float4 v = *(const float4*)(wp + u);
        ushort4v p = { f2bf(v.x), f2bf(v.y), f2bf(v.z), f2bf(v.w) };
        *(ushort4v*)&L[kr][cb + u] = p;
    }
    __syncthreads();
    const int nr = t >> 2, kb = (t & 3) * 16;
    short8 lo, hi;
#pragma unroll
    for (int u = 0; u < 8; ++u) lo[u] = (short)L[kb + u][nr];
#pragma unroll
    for (int u = 0; u < 8; ++u) hi[u] = (short)L[kb + 8 + u][nr];
    unsigned short* op = Wt + (size_t)(n0 + nr) * K + k0 + kb;
    *(short8*)op       = lo;
    *(short8*)(op + 8) = hi;
}

// ---------------------------------------------------------------------------
// RoPE + bf16 convert for Q,K. Q pre-scaled by 0.125*log2(e) for exp2 softmax.
// Angles computed in revolutions: rev = fract(s * invf/(2π)), then v_sin/v_cos.
// One thread per (s, 4 consecutive j). grid = S*128/256 blocks.
// ---------------------------------------------------------------------------
__global__ __launch_bounds__(256) void rope_cvt_kernel(
    const float* __restrict__ qkv,
    unsigned short* __restrict__ Qb,
    unsigned short* __restrict__ Kb)
{
    const int idx = blockIdx.x * 256 + threadIdx.x;   // S*128 total
    const int j   = (idx & 127) * 4;
    const int s   = idx >> 7;
    const float* row = qkv + (size_t)s * QKV_N;
    unsigned short* qo = Qb + (size_t)s * DIM;
    unsigned short* ko = Kb + (size_t)s * DIM;
    const float sf = (float)s;
    const float QSCALE = 0.18033688011112042f;           // 0.125 * log2(e)
    const float C1 = -0.025952563241307517f;             // -log2(10000)/512
    const float INV2PI = 0.15915494309189535f;

    float cs[4], sn[4];
#pragma unroll
    for (int e = 0; e < 4; ++e) {
        const float invf2pi = exp2f((float)(j + e) * C1) * INV2PI;
        float rev = sf * invf2pi;
        rev -= floorf(rev);
        sn[e] = __builtin_amdgcn_sinf(rev);   // sin(2π·rev)
        cs[e] = __builtin_amdgcn_cosf(rev);
    }
    float4 q1 = *(const float4*)(row + j);
    float4 q2 = *(const float4*)(row + 512 + j);
    float4 k1 = *(const float4*)(row + DIM + j);
    float4 k2 = *(const float4*)(row + DIM + 512 + j);
    float x1[4] = {q1.x, q1.y, q1.z, q1.w};
    float x2[4] = {q2.x, q2.y, q2.z, q2.w};
    float y1[4] = {k1.x, k1.y, k1.z, k1.w};
    float y2[4] = {k2.x, k2.y, k2.z, k2.w};
    ushort4v qa, qb4, ka, kb4;
#pragma unroll
    for (int e = 0; e < 4; ++e) {
        qa[e]  = f2bf((x1[e] * cs[e] - x2[e] * sn[e]) * QSCALE);
        qb4[e] = f2bf((x2[e] * cs[e] + x1[e] * sn[e]) * QSCALE);
        ka[e]  = f2bf(y1[e] * cs[e] - y2[e] * sn[e]);
        kb4[e] = f2bf(y2[e] * cs[e] + y1[e] * sn[e]);
    }
    *(ushort4v*)(qo + j)       = qa;
    *(ushort4v*)(qo + 512 + j) = qb4;
    *(ushort4v*)(ko + j)       = ka;
    *(ushort4v*)(ko + 512 + j) = kb4;
}

// ---------------------------------------------------------------------------
// V transpose + convert: qkv[:, 2048+c] -> Vt[c][s] bf16. 64×64 tiles.
// grid = (16 col-tiles, S/64 row-tiles).
// ---------------------------------------------------------------------------
__global__ __launch_bounds__(256) void vtrans_kernel(
    const float* __restrict__ qkv, unsigned short* __restrict__ Vt)
{
    __shared__ unsigned short L[64][72];
    const int t  = threadIdx.x;
    const int bs = blockIdx.y * 64;
    const int c0 = blockIdx.x * 64;

    const int sl = t >> 2, cb = (t & 3) * 16;
    const float* vp = qkv + (size_t)(bs + sl) * QKV_N + 2 * DIM + c0 + cb;
#pragma unroll
    for (int u = 0; u < 16; u += 4) {
        float4 v = *(const float4*)(vp + u);
        ushort4v p = { f2bf(v.x), f2bf(v.y), f2bf(v.z), f2bf(v.w) };
        *(ushort4v*)&L[sl][cb + u] = p;
    }
    __syncthreads();
    const int cl = t >> 2, sb = (t & 3) * 16;
    short8 lo, hi;
#pragma unroll
    for (int u = 0; u < 8; ++u) lo[u] = (short)L[sb + u][cl];
#pragma unroll
    for (int u = 0; u < 8; ++u) hi[u] = (short)L[sb + 8 + u][cl];
    unsigned short* op = Vt + (size_t)(c0 + cl) * S_LEN + bs + sb;
    *(short8*)op       = lo;
    *(short8*)(op + 8) = hi;
}

// ---------------------------------------------------------------------------
// MFMA flash attention (bf16, causal). Unchanged from round 2 except the
// epilogue now writes bf16 (feeds the bf16 proj GEMM directly).
// ---------------------------------------------------------------------------
__global__ __launch_bounds__(256) void attn_mfma_kernel(
    const unsigned short* __restrict__ Qb,
    const unsigned short* __restrict__ Kb,
    const unsigned short* __restrict__ Vt,
    unsigned short* __restrict__ outb)
{
    __shared__ unsigned short Ks[64][72];   // [c][d]
    __shared__ unsigned short Vs[64][72];   // [d][c]
    __shared__ unsigned short Ps[64][72];   // [m][c]

    const int t    = threadIdx.x;
    const int w    = t >> 6;
    const int lane = t & 63;
    const int ln   = lane & 15;
    const int quad = lane >> 4;
    const int h    = blockIdx.y;
    const int qt   = (int)(gridDim.x - 1) - (int)blockIdx.x;  // heavy tiles first
    const int q0   = qt * 64;

    short8 qf[2];
    {
        const unsigned short* qp = Qb + (size_t)(q0 + w * 16 + ln) * DIM + h * HD + quad * 8;
        qf[0] = *(const short8*)qp;
        qf[1] = *(const short8*)(qp + 32);
    }

    f32x4 o[4];
#pragma unroll
    for (int db = 0; db < 4; ++db) o[db] = (f32x4){0.f, 0.f, 0.f, 0.f};
    float mrow[4] = {-1e30f, -1e30f, -1e30f, -1e30f};
    float lrow[4] = {0.f, 0.f, 0.f, 0.f};

    for (int kt = 0; kt <= qt; ++kt) {
        const int k0 = kt * 64;
        __syncthreads();
        {
            const int c   = t >> 2;
            const int off = (t & 3) * 16;
            const unsigned short* kp = Kb + (size_t)(k0 + c) * DIM + h * HD + off;
            *(short8*)&Ks[c][off]     = *(const short8*)kp;
            *(short8*)&Ks[c][off + 8] = *(const short8*)(kp + 8);
            const unsigned short* vp = Vt + (size_t)(h * HD + c) * S_LEN + k0 + off;
            *(short8*)&Vs[c][off]     = *(const short8*)vp;
            *(short8*)&Vs[c][off + 8] = *(const short8*)(vp + 8);
        }
        __syncthreads();

        f32x4 sc[4];
#pragma unroll
        for (int nb = 0; nb < 4; ++nb) sc[nb] = (f32x4){0.f, 0.f, 0.f, 0.f};
#pragma unroll
        for (int kk = 0; kk < 2; ++kk) {
#pragma unroll
            for (int nb = 0; nb < 4; ++nb) {
                short8 bfr = *(const short8*)&Ks[nb * 16 + ln][kk * 32 + quad * 8];
                sc[nb] = __builtin_amdgcn_mfma_f32_16x16x32_bf16(qf[kk], bfr, sc[nb], 0, 0, 0);
            }
        }

        if (kt == qt) {
#pragma unroll
            for (int nb = 0; nb < 4; ++nb) {
                const int col = nb * 16 + ln;
#pragma unroll
                for (int r = 0; r < 4; ++r)
                    if (col > w * 16 + quad * 4 + r) sc[nb][r] = -1e30f;
            }
        }

#pragma unroll
        for (int r = 0; r < 4; ++r) {
            float tm = fmaxf(fmaxf(sc[0][r], sc[1][r]), fmaxf(sc[2][r], sc[3][r]));
            tm = fmaxf(tm, __shfl_xor(tm, 1));
            tm = fmaxf(tm, __shfl_xor(tm, 2));
            tm = fmaxf(tm, __shfl_xor(tm, 4));
            tm = fmaxf(tm, __shfl_xor(tm, 8));
            const float mnew = fmaxf(mrow[r], tm);
            const float al   = exp2f(mrow[r] - mnew);
            mrow[r] = mnew;
            float ps = 0.f;
#pragma unroll
            for (int nb = 0; nb < 4; ++nb) {
                const float p = exp2f(sc[nb][r] - mnew);
                ps += p;
                Ps[w * 16 + quad * 4 + r][nb * 16 + ln] = f2bf(p);
            }
            ps += __shfl_xor(ps, 1);
            ps += __shfl_xor(ps, 2);
            ps += __shfl_xor(ps, 4);
            ps += __shfl_xor(ps, 8);
            lrow[r] = lrow[r] * al + ps;
#pragma unroll
            for (int db = 0; db < 4; ++db) o[db][r] *= al;
        }

#pragma unroll
        for (int kk = 0; kk < 2; ++kk) {
            short8 pa = *(const short8*)&Ps[w * 16 + ln][kk * 32 + quad * 8];
#pragma unroll
            for (int db = 0; db < 4; ++db) {
                short8 vb = *(const short8*)&Vs[db * 16 + ln][kk * 32 + quad * 8];
                o[db] = __builtin_amdgcn_mfma_f32_16x16x32_bf16(pa, vb, o[db], 0, 0, 0);
            }
        }
    }

#pragma unroll
    for (int r = 0; r < 4; ++r) {
        const float inv = 1.0f / lrow[r];
        unsigned short* op = outb + (size_t)(q0 + w * 16 + quad * 4 + r) * DIM + h * HD;
#pragma unroll
        for (int db = 0; db < 4; ++db)
            op[db * 16 + ln] = f2bf(o[db][r] * inv);
    }
}

// ---------------------------------------------------------------------------
// LayerNorm per row (unchanged)
// ---------------------------------------------------------------------------
__global__ __launch_bounds__(256) void ln_kernel(
    const float* __restrict__ in, const float* __restrict__ gamma,
    const float* __restrict__ beta, float* __restrict__ out)
{
    const int row = blockIdx.x;
    const int t = threadIdx.x;
    const float4 v = *(const float4*)&in[(size_t)row * DIM + t * 4];
    float s  = v.x + v.y + v.z + v.w;
    float sq = v.x * v.x + v.y * v.y + v.z * v.z + v.w * v.w;
#pragma unroll
    for (int off = 1; off < 64; off <<= 1) {
        s  += __shfl_xor(s, off);
        sq += __shfl_xor(sq, off);
    }
    __shared__ float red[8];
    const int wv = t >> 6, ln = t & 63;
    if (ln == 0) { red[wv] = s; red[4 + wv] = sq; }
    __syncthreads();
    s  = red[0] + red[1] + red[2] + red[3];
    sq = red[4] + red[5] + red[6] + red[7];
    const float mu  = s * (1.0f / DIM);
    const float var = sq * (1.0f / DIM) - mu * mu;
    const float rs  = rsqrtf(var + 1e-5f);
    const float4 g = *(const float4*)&gamma[t * 4];
    const float4 b = *(const float4*)&beta[t * 4];
    float4 o = { (v.x - mu) * rs * g.x + b.x,
                 (v.y - mu) * rs * g.y + b.y,
                 (v.z - mu) * rs * g.z + b.z,
                 (v.w - mu) * rs * g.w + b.w };
    *(float4*)&out[(size_t)row * DIM + t * 4] = o;
}

// ---------------------------------------------------------------------------
extern "C" void kernel_launch(void* const* d_in, const int* in_sizes, int n_in,
                              void* d_out, int out_size, void* d_ws, size_t ws_size,
                              hipStream_t stream)
{
    const float* x     = (const float*)d_in[0];
    const float* Wqkv  = (const float*)d_in[1];
    const float* bqkv  = (const float*)d_in[2];
    const float* Wo    = (const float*)d_in[3];
    const float* bo    = (const float*)d_in[4];
    const float* gamma = (const float*)d_in[5];
    const float* beta  = (const float*)d_in[6];
    float* out = (float*)d_out;

    // ws layout (bytes):
    // [0, 48M):   qkv fp32 (dead after rope/vtrans; then attnb bf16 at [0,8M),
    //             proj fp32 at [8M,24M))
    // [48M, 56M): Qb bf16   [56M,64M): Kb bf16   [64M,72M): Vt bf16
    // [72M, 80M): xb bf16   [80M,86M): WqkvT bf16   [86M,88M): WoT bf16
    char* base = (char*)d_ws;
    float* qkv = (float*)base;
    unsigned short* attnb = (unsigned short*)base;
    float* proj = (float*)(base + (size_t)8 * 1024 * 1024);
    unsigned short* Qb    = (unsigned short*)(base + (size_t)48 * 1024 * 1024);
    unsigned short* Kb    = (unsigned short*)(base + (size_t)56 * 1024 * 1024);
    unsigned short* Vt    = (unsigned short*)(base + (size_t)64 * 1024 * 1024);
    unsigned short* xb    = (unsigned short*)(base + (size_t)72 * 1024 * 1024);
    unsigned short* WqkvT = (unsigned short*)(base + (size_t)80 * 1024 * 1024);
    unsigned short* WoT   = (unsigned short*)(base + (size_t)86 * 1024 * 1024);

    cvt_bf16_kernel<<<(S_LEN * DIM) / (256 * 8), 256, 0, stream>>>(x, xb);
    wtrans_kernel<<<dim3(QKV_N / 64, DIM / 64), 256, 0, stream>>>(Wqkv, WqkvT, DIM, QKV_N);
    wtrans_kernel<<<dim3(DIM / 64, DIM / 64), 256, 0, stream>>>(Wo, WoT, DIM, DIM);

    gemm_mfma_kernel<<<dim3(QKV_N / 128, S_LEN / 128), 256, 0, stream>>>(
        xb, WqkvT, bqkv, qkv, S_LEN, QKV_N, DIM);

    rope_cvt_kernel<<<(S_LEN * 128) / 256, 256, 0, stream>>>(qkv, Qb, Kb);
    vtrans_kernel<<<dim3(16, S_LEN / 64), 256, 0, stream>>>(qkv, Vt);

    attn_mfma_kernel<<<dim3(S_LEN / 64, NH), 256, 0, stream>>>(Qb, Kb, Vt, attnb);

    gemm_mfma_kernel<<<dim3(DIM / 128, S_LEN / 128), 256, 0, stream>>>(
        attnb, WoT, bo, proj, S_LEN, DIM, DIM);

    ln_kernel<<<S_LEN, 256, 0, stream>>>(proj, gamma, beta, out);
}

// Round 4
// 277.250 us; speedup vs baseline: 6.0666x; 1.4893x over previous
//
#include <hip/hip_runtime.h>
#include <cstdint>
#include <cstddef>

#define S_LEN 4096
#define DIM   1024
#define NH    16
#define HD    64
#define QKV_N 3072

typedef __attribute__((ext_vector_type(8))) short short8;     // 8 bf16
typedef __attribute__((ext_vector_type(4))) float f32x4;      // MFMA C/D frag
typedef __attribute__((ext_vector_type(4))) unsigned short ushort4v;

__device__ inline unsigned short f2bf(float x) {   // RNE float->bf16
    unsigned int u = __builtin_bit_cast(unsigned int, x);
    u += 0x7fffu + ((u >> 16) & 1u);
    return (unsigned short)(u >> 16);
}

// async global->LDS, 16B per lane; LDS dest = wave-uniform base + lane*16
__device__ inline void gl_lds16(const void* g, void* l) {
    __builtin_amdgcn_global_load_lds(
        (const __attribute__((address_space(1))) void*)g,
        (__attribute__((address_space(3))) void*)l, 16, 0, 0);
}

// ---------------------------------------------------------------------------
// bf16 MFMA GEMM (m97 structure): C = A @ Bt^T + bias.
// ---------------------------------------------------------------------------
__global__ __launch_bounds__(256) void gemm_mfma_kernel(
    const unsigned short* __restrict__ A,
    const unsigned short* __restrict__ Bt,
    const float* __restrict__ bias,
    float* __restrict__ C,
    int M, int N, int K)
{
    __shared__ unsigned short As[128 * 32];   // [m][k], k contiguous (no pad: glds)
    __shared__ unsigned short Bs[128 * 32];   // [n][k]

    const int t    = threadIdx.x;
    const int w    = t >> 6;
    const int lane = t & 63;
    const int ln   = lane & 15;
    const int quad = lane >> 4;
    const int bm   = blockIdx.y * 128;
    const int bn   = blockIdx.x * 128;
    const int wm   = (w & 1) * 64;
    const int wn   = (w >> 1) * 64;

    f32x4 acc[4][4];
#pragma unroll
    for (int i = 0; i < 4; ++i)
#pragma unroll
        for (int j = 0; j < 4; ++j) acc[i][j] = (f32x4){0.f, 0.f, 0.f, 0.f};

    const int lr = lane >> 2;
    const int lc = (lane & 3) * 8;
    const unsigned short* ga = A  + (size_t)(bm + w * 32 + lr) * K + lc;
    const unsigned short* gb = Bt + (size_t)(bn + w * 32 + lr) * K + lc;
    unsigned short* la = &As[(w * 32) * 32];
    unsigned short* lb = &Bs[(w * 32) * 32];

    for (int k0 = 0; k0 < K; k0 += 32) {
        gl_lds16(ga,            la);
        gl_lds16(ga + 16 * K,   la + 16 * 32);
        gl_lds16(gb,            lb);
        gl_lds16(gb + 16 * K,   lb + 16 * 32);
        ga += 32; gb += 32;
        __syncthreads();

        short8 af[4], bf[4];
#pragma unroll
        for (int i = 0; i < 4; ++i)
            af[i] = *(const short8*)&As[(wm + i * 16 + ln) * 32 + quad * 8];
#pragma unroll
        for (int j = 0; j < 4; ++j)
            bf[j] = *(const short8*)&Bs[(wn + j * 16 + ln) * 32 + quad * 8];
#pragma unroll
        for (int i = 0; i < 4; ++i)
#pragma unroll
            for (int j = 0; j < 4; ++j)
                acc[i][j] = __builtin_amdgcn_mfma_f32_16x16x32_bf16(af[i], bf[j], acc[i][j], 0, 0, 0);
        __syncthreads();
    }

#pragma unroll
    for (int j = 0; j < 4; ++j) {
        const int col = bn + wn + j * 16 + ln;
        const float bv = bias[col];
#pragma unroll
        for (int i = 0; i < 4; ++i) {
            const int row0 = bm + wm + i * 16 + quad * 4;
#pragma unroll
            for (int r = 0; r < 4; ++r)
                C[(size_t)(row0 + r) * N + col] = acc[i][j][r] + bv;
        }
    }
}

// ---------------------------------------------------------------------------
__global__ __launch_bounds__(256) void cvt_bf16_kernel(
    const float* __restrict__ in, unsigned short* __restrict__ out)
{
    const size_t i = ((size_t)blockIdx.x * 256 + threadIdx.x) * 8;
    float4 a = *(const float4*)(in + i);
    float4 b = *(const float4*)(in + i + 4);
    short8 p = { (short)f2bf(a.x), (short)f2bf(a.y), (short)f2bf(a.z), (short)f2bf(a.w),
                 (short)f2bf(b.x), (short)f2bf(b.y), (short)f2bf(b.z), (short)f2bf(b.w) };
    *(short8*)(out + i) = p;
}

// ---------------------------------------------------------------------------
// Weight transpose + convert: W (K×N fp32) -> Wt (N×K bf16). 64×64 tiles.
// ---------------------------------------------------------------------------
__global__ __launch_bounds__(256) void wtrans_kernel(
    const float* __restrict__ W, unsigned short* __restrict__ Wt, int K, int N)
{
    __shared__ unsigned short L[64][72];
    const int t  = threadIdx.x;
    const int k0 = blockIdx.y * 64;
    const int n0 = blockIdx.x * 64;

    const int kr = t >> 2, cb = (t & 3) * 16;
    const float* wp = W + (size_t)(k0 + kr) * N + n0 + cb;
#pragma unroll
    for (int u = 0; u < 16; u += 4) {
        float4 v = *(const float4*)(wp + u);
        ushort4v p = { f2bf(v.x), f2bf(v.y), f2bf(v.z), f2bf(v.w) };
        *(ushort4v*)&L[kr][cb + u] = p;
    }
    __syncthreads();
    const int nr = t >> 2, kb = (t & 3) * 16;
    short8 lo, hi;
#pragma unroll
    for (int u = 0; u < 8; ++u) lo[u] = (short)L[kb + u][nr];
#pragma unroll
    for (int u = 0; u < 8; ++u) hi[u] = (short)L[kb + 8 + u][nr];
    unsigned short* op = Wt + (size_t)(n0 + nr) * K + k0 + kb;
    *(short8*)op       = lo;
    *(short8*)(op + 8) = hi;
}

// ---------------------------------------------------------------------------
// RoPE + bf16 convert for Q,K (Q pre-scaled by 0.125*log2(e)).
// ---------------------------------------------------------------------------
__global__ __launch_bounds__(256) void rope_cvt_kernel(
    const float* __restrict__ qkv,
    unsigned short* __restrict__ Qb,
    unsigned short* __restrict__ Kb)
{
    const int idx = blockIdx.x * 256 + threadIdx.x;   // S*128 total
    const int j   = (idx & 127) * 4;
    const int s   = idx >> 7;
    const float* row = qkv + (size_t)s * QKV_N;
    unsigned short* qo = Qb + (size_t)s * DIM;
    unsigned short* ko = Kb + (size_t)s * DIM;
    const float sf = (float)s;
    const float QSCALE = 0.18033688011112042f;           // 0.125 * log2(e)
    const float C1 = -0.025952563241307517f;             // -log2(10000)/512
    const float INV2PI = 0.15915494309189535f;

    float cs[4], sn[4];
#pragma unroll
    for (int e = 0; e < 4; ++e) {
        const float invf2pi = exp2f((float)(j + e) * C1) * INV2PI;
        float rev = sf * invf2pi;
        rev -= floorf(rev);
        sn[e] = __builtin_amdgcn_sinf(rev);
        cs[e] = __builtin_amdgcn_cosf(rev);
    }
    float4 q1 = *(const float4*)(row + j);
    float4 q2 = *(const float4*)(row + 512 + j);
    float4 k1 = *(const float4*)(row + DIM + j);
    float4 k2 = *(const float4*)(row + DIM + 512 + j);
    float x1[4] = {q1.x, q1.y, q1.z, q1.w};
    float x2[4] = {q2.x, q2.y, q2.z, q2.w};
    float y1[4] = {k1.x, k1.y, k1.z, k1.w};
    float y2[4] = {k2.x, k2.y, k2.z, k2.w};
    ushort4v qa, qb4, ka, kb4;
#pragma unroll
    for (int e = 0; e < 4; ++e) {
        qa[e]  = f2bf((x1[e] * cs[e] - x2[e] * sn[e]) * QSCALE);
        qb4[e] = f2bf((x2[e] * cs[e] + x1[e] * sn[e]) * QSCALE);
        ka[e]  = f2bf(y1[e] * cs[e] - y2[e] * sn[e]);
        kb4[e] = f2bf(y2[e] * cs[e] + y1[e] * sn[e]);
    }
    *(ushort4v*)(qo + j)       = qa;
    *(ushort4v*)(qo + 512 + j) = qb4;
    *(ushort4v*)(ko + j)       = ka;
    *(ushort4v*)(ko + 512 + j) = kb4;
}

// ---------------------------------------------------------------------------
// V transpose + convert: qkv[:, 2048+c] -> Vt[c][s] bf16. 64×64 tiles.
// ---------------------------------------------------------------------------
__global__ __launch_bounds__(256) void vtrans_kernel(
    const float* __restrict__ qkv, unsigned short* __restrict__ Vt)
{
    __shared__ unsigned short L[64][72];
    const int t  = threadIdx.x;
    const int bs = blockIdx.y * 64;
    const int c0 = blockIdx.x * 64;

    const int sl = t >> 2, cb = (t & 3) * 16;
    const float* vp = qkv + (size_t)(bs + sl) * QKV_N + 2 * DIM + c0 + cb;
#pragma unroll
    for (int u = 0; u < 16; u += 4) {
        float4 v = *(const float4*)(vp + u);
        ushort4v p = { f2bf(v.x), f2bf(v.y), f2bf(v.z), f2bf(v.w) };
        *(ushort4v*)&L[sl][cb + u] = p;
    }
    __syncthreads();
    const int cl = t >> 2, sb = (t & 3) * 16;
    short8 lo, hi;
#pragma unroll
    for (int u = 0; u < 8; ++u) lo[u] = (short)L[sb + u][cl];
#pragma unroll
    for (int u = 0; u < 8; ++u) hi[u] = (short)L[sb + 8 + u][cl];
    unsigned short* op = Vt + (size_t)(c0 + cl) * S_LEN + bs + sb;
    *(short8*)op       = lo;
    *(short8*)(op + 8) = hi;
}

// ---------------------------------------------------------------------------
// MFMA flash attention, transposed-score formulation.
//   S^T = K·Q^T  (A=K-frag, B=Q-frag)  -> score col = q-row = ln:
//     per-lane softmax state, 2 shfl per reduction, packed b64 P-writes.
//   O^T = V^T·P^T (A=V-frag, B=P-frag) -> alpha rescale is per-lane scalar.
// Block = (pair p, head): q-tiles 63-p then p (uniform 65 k-iters per block).
// Register prefetch of next K/V tile hides global latency across the barrier.
// ---------------------------------------------------------------------------
__global__ __launch_bounds__(256) void attn_mfma_kernel(
    const unsigned short* __restrict__ Qb,
    const unsigned short* __restrict__ Kb,
    const unsigned short* __restrict__ Vt,
    unsigned short* __restrict__ outb)
{
    __shared__ unsigned short Ks[64][72];       // [key][d]
    __shared__ unsigned short Vs[64][72];       // [d][key]
    __shared__ unsigned short Ps[4][16][72];    // per-wave [m][key]

    const int t    = threadIdx.x;
    const int w    = t >> 6;
    const int lane = t & 63;
    const int ln   = lane & 15;
    const int quad = lane >> 4;
    const int h    = blockIdx.y;
    const int p    = blockIdx.x;     // 0..31

    const int sc_ = t >> 2;          // staging: key (Ks) / d (Vs)
    const int so  = (t & 3) * 16;    // staging: 16-ushort chunk offset

#pragma unroll
    for (int phase = 0; phase < 2; ++phase) {
        const int qt = phase == 0 ? (63 - p) : p;
        const int q0 = qt * 64;

        short8 qf[2];
        {
            const unsigned short* qp = Qb + (size_t)(q0 + w * 16 + ln) * DIM + h * HD + quad * 8;
            qf[0] = *(const short8*)qp;
            qf[1] = *(const short8*)(qp + 32);
        }

        f32x4 o[4];
#pragma unroll
        for (int db = 0; db < 4; ++db) o[db] = (f32x4){0.f, 0.f, 0.f, 0.f};
        float mrow = -1e30f, lrow = 0.f;

        // prefetch tile 0
        short8 kr0, kr1, vr0, vr1;
        {
            const unsigned short* kp = Kb + (size_t)sc_ * DIM + h * HD + so;
            kr0 = *(const short8*)kp;  kr1 = *(const short8*)(kp + 8);
            const unsigned short* vp = Vt + (size_t)(h * HD + sc_) * S_LEN + so;
            vr0 = *(const short8*)vp;  vr1 = *(const short8*)(vp + 8);
        }

        for (int kt = 0; kt <= qt; ++kt) {
            __syncthreads();   // prior tile's Ks/Vs reads complete
            *(short8*)&Ks[sc_][so]     = kr0;
            *(short8*)&Ks[sc_][so + 8] = kr1;
            *(short8*)&Vs[sc_][so]     = vr0;
            *(short8*)&Vs[sc_][so + 8] = vr1;
            if (kt < qt) {   // prefetch next tile (overlaps barrier + compute)
                const int k1 = (kt + 1) * 64;
                const unsigned short* kp = Kb + (size_t)(k1 + sc_) * DIM + h * HD + so;
                kr0 = *(const short8*)kp;  kr1 = *(const short8*)(kp + 8);
                const unsigned short* vp = Vt + (size_t)(h * HD + sc_) * S_LEN + k1 + so;
                vr0 = *(const short8*)vp;  vr1 = *(const short8*)(vp + 8);
            }
            __syncthreads();   // staging visible

            // S^T = K·Q^T : sc[kb] holds s(key=kb*16+quad*4+r, m=ln)
            f32x4 sc[4];
#pragma unroll
            for (int kb = 0; kb < 4; ++kb) sc[kb] = (f32x4){0.f, 0.f, 0.f, 0.f};
#pragma unroll
            for (int kk = 0; kk < 2; ++kk) {
#pragma unroll
                for (int kb = 0; kb < 4; ++kb) {
                    short8 kf = *(const short8*)&Ks[kb * 16 + ln][kk * 32 + quad * 8];
                    sc[kb] = __builtin_amdgcn_mfma_f32_16x16x32_bf16(kf, qf[kk], sc[kb], 0, 0, 0);
                }
            }

            if (kt == qt) {   // diagonal: mask key > q-row
#pragma unroll
                for (int kb = 0; kb < 4; ++kb) {
                    const int key = kb * 16 + quad * 4;
#pragma unroll
                    for (int r = 0; r < 4; ++r)
                        if (key + r > w * 16 + ln) sc[kb][r] = -1e30f;
                }
            }

            // per-lane online softmax (row m = ln; scores pre-scaled by log2e)
            float tm = -1e30f;
#pragma unroll
            for (int kb = 0; kb < 4; ++kb)
#pragma unroll
                for (int r = 0; r < 4; ++r) tm = fmaxf(tm, sc[kb][r]);
            tm = fmaxf(tm, __shfl_xor(tm, 16));
            tm = fmaxf(tm, __shfl_xor(tm, 32));
            const float mnew = fmaxf(mrow, tm);
            const float al   = exp2f(mrow - mnew);
            mrow = mnew;
            float ps = 0.f;
#pragma unroll
            for (int kb = 0; kb < 4; ++kb) {
                ushort4v pk;
#pragma unroll
                for (int r = 0; r < 4; ++r) {
                    const float pv = exp2f(sc[kb][r] - mnew);
                    ps += pv;
                    pk[r] = f2bf(pv);
                }
                *(ushort4v*)&Ps[w][ln][kb * 16 + quad * 4] = pk;   // b64 packed
            }
            ps += __shfl_xor(ps, 16);
            ps += __shfl_xor(ps, 32);
            lrow = lrow * al + ps;
#pragma unroll
            for (int db = 0; db < 4; ++db) o[db] *= al;

            // O^T += V^T·P^T
#pragma unroll
            for (int kk = 0; kk < 2; ++kk) {
                short8 pf = *(const short8*)&Ps[w][ln][kk * 32 + quad * 8];
#pragma unroll
                for (int db = 0; db < 4; ++db) {
                    short8 vf = *(const short8*)&Vs[db * 16 + ln][kk * 32 + quad * 8];
                    o[db] = __builtin_amdgcn_mfma_f32_16x16x32_bf16(vf, pf, o[db], 0, 0, 0);
                }
            }
        }

        // epilogue: O^T -> LDS (wave-local) -> coalesced bf16 rows
        const float inv = 1.0f / lrow;
#pragma unroll
        for (int db = 0; db < 4; ++db) {
            ushort4v pk;
#pragma unroll
            for (int r = 0; r < 4; ++r) pk[r] = f2bf(o[db][r] * inv);
            *(ushort4v*)&Ps[w][ln][db * 16 + quad * 4] = pk;
        }
        {
            const int m  = lane >> 2;
            const int d0 = (lane & 3) * 16;
            short8 r0 = *(const short8*)&Ps[w][m][d0];
            short8 r1 = *(const short8*)&Ps[w][m][d0 + 8];
            unsigned short* op = outb + (size_t)(q0 + w * 16 + m) * DIM + h * HD + d0;
            *(short8*)op       = r0;
            *(short8*)(op + 8) = r1;
        }
    }
}

// ---------------------------------------------------------------------------
__global__ __launch_bounds__(256) void ln_kernel(
    const float* __restrict__ in, const float* __restrict__ gamma,
    const float* __restrict__ beta, float* __restrict__ out)
{
    const int row = blockIdx.x;
    const int t = threadIdx.x;
    const float4 v = *(const float4*)&in[(size_t)row * DIM + t * 4];
    float s  = v.x + v.y + v.z + v.w;
    float sq = v.x * v.x + v.y * v.y + v.z * v.z + v.w * v.w;
#pragma unroll
    for (int off = 1; off < 64; off <<= 1) {
        s  += __shfl_xor(s, off);
        sq += __shfl_xor(sq, off);
    }
    __shared__ float red[8];
    const int wv = t >> 6, ln = t & 63;
    if (ln == 0) { red[wv] = s; red[4 + wv] = sq; }
    __syncthreads();
    s  = red[0] + red[1] + red[2] + red[3];
    sq = red[4] + red[5] + red[6] + red[7];
    const float mu  = s * (1.0f / DIM);
    const float var = sq * (1.0f / DIM) - mu * mu;
    const float rs  = rsqrtf(var + 1e-5f);
    const float4 g = *(const float4*)&gamma[t * 4];
    const float4 b = *(const float4*)&beta[t * 4];
    float4 o = { (v.x - mu) * rs * g.x + b.x,
                 (v.y - mu) * rs * g.y + b.y,
                 (v.z - mu) * rs * g.z + b.z,
                 (v.w - mu) * rs * g.w + b.w };
    *(float4*)&out[(size_t)row * DIM + t * 4] = o;
}

// ---------------------------------------------------------------------------
extern "C" void kernel_launch(void* const* d_in, const int* in_sizes, int n_in,
                              void* d_out, int out_size, void* d_ws, size_t ws_size,
                              hipStream_t stream)
{
    const float* x     = (const float*)d_in[0];
    const float* Wqkv  = (const float*)d_in[1];
    const float* bqkv  = (const float*)d_in[2];
    const float* Wo    = (const float*)d_in[3];
    const float* bo    = (const float*)d_in[4];
    const float* gamma = (const float*)d_in[5];
    const float* beta  = (const float*)d_in[6];
    float* out = (float*)d_out;

    char* base = (char*)d_ws;
    float* qkv = (float*)base;
    unsigned short* attnb = (unsigned short*)base;
    float* proj = (float*)(base + (size_t)8 * 1024 * 1024);
    unsigned short* Qb    = (unsigned short*)(base + (size_t)48 * 1024 * 1024);
    unsigned short* Kb    = (unsigned short*)(base + (size_t)56 * 1024 * 1024);
    unsigned short* Vt    = (unsigned short*)(base + (size_t)64 * 1024 * 1024);
    unsigned short* xb    = (unsigned short*)(base + (size_t)72 * 1024 * 1024);
    unsigned short* WqkvT = (unsigned short*)(base + (size_t)80 * 1024 * 1024);
    unsigned short* WoT   = (unsigned short*)(base + (size_t)86 * 1024 * 1024);

    cvt_bf16_kernel<<<(S_LEN * DIM) / (256 * 8), 256, 0, stream>>>(x, xb);
    wtrans_kernel<<<dim3(QKV_N / 64, DIM / 64), 256, 0, stream>>>(Wqkv, WqkvT, DIM, QKV_N);
    wtrans_kernel<<<dim3(DIM / 64, DIM / 64), 256, 0, stream>>>(Wo, WoT, DIM, DIM);

    gemm_mfma_kernel<<<dim3(QKV_N / 128, S_LEN / 128), 256, 0, stream>>>(
        xb, WqkvT, bqkv, qkv, S_LEN, QKV_N, DIM);

    rope_cvt_kernel<<<(S_LEN * 128) / 256, 256, 0, stream>>>(qkv, Qb, Kb);
    vtrans_kernel<<<dim3(16, S_LEN / 64), 256, 0, stream>>>(qkv, Vt);

    attn_mfma_kernel<<<dim3(32, NH), 256, 0, stream>>>(Qb, Kb, Vt, attnb);

    gemm_mfma_kernel<<<dim3(DIM / 128, S_LEN / 128), 256, 0, stream>>>(
        attnb, WoT, bo, proj, S_LEN, DIM, DIM);

    ln_kernel<<<S_LEN, 256, 0, stream>>>(proj, gamma, beta, out);
}